// Round 7
// baseline (230.728 us; speedup 1.0000x reference)
//
#include <hip/hip_runtime.h>
#include <hip/hip_bf16.h>
#include <math.h>

#define B_ 16
#define D_ 768
#define N_ 1024
#define Z_ 256
#define TOPK_ 512
#define HW_ 32
#define EPS_ 1e-5f

typedef unsigned int uint;
typedef unsigned short ushort;
typedef __attribute__((ext_vector_type(4))) short short4v;
typedef __attribute__((ext_vector_type(8))) short bf16x8;
typedef __attribute__((ext_vector_type(4))) float f32x4;
typedef __attribute__((ext_vector_type(4))) int int4v;

__device__ __forceinline__ ushort f2bf(float v) {
  uint b = __float_as_uint(v);
  b += 0x7FFFu + ((b >> 16) & 1u);
  return (ushort)(b >> 16);
}
__device__ __forceinline__ float bf2f(ushort h) { return __uint_as_float(((uint)h) << 16); }
__device__ __forceinline__ int pk2(ushort a, ushort b) { return (int)((uint)a | ((uint)b << 16)); }

// ---------------- k_wsum: partial column-sums of wp: wsum4[h][z] = sum_{d in h-quarter} wp[d][z]
__global__ __launch_bounds__(256) void k_wsum(const float* __restrict__ wp,
                                              float* __restrict__ wsum4) {
  int z = threadIdx.x, h = blockIdx.x;
  float s = 0.f;
#pragma unroll 8
  for (int d = h * 192; d < (h + 1) * 192; ++d) s += wp[(size_t)d * Z_ + z];
  wsum4[h * Z_ + z] = s;
}

// ---------------- k_db: db = cb + cw@bp ; bg = cb + cw@mtk ; M1[o] = sum_z wsum[z]*cw[o][z]
__global__ __launch_bounds__(256) void k_db(const float* __restrict__ cw,
                                            const float* __restrict__ cb,
                                            const float* __restrict__ bp,
                                            const float* __restrict__ mtk,
                                            const float* __restrict__ wsum4,
                                            float* __restrict__ db,
                                            float* __restrict__ bg,
                                            float* __restrict__ M1) {
  __shared__ float s1[4], s2[4], s3[4];
  int o = blockIdx.x, tid = threadIdx.x;
  float c = cw[o * Z_ + tid];
  float ws = wsum4[tid] + wsum4[Z_ + tid] + wsum4[2 * Z_ + tid] + wsum4[3 * Z_ + tid];
  float a1 = c * bp[tid], a2 = c * mtk[tid], a3 = c * ws;
#pragma unroll
  for (int m = 32; m > 0; m >>= 1) {
    a1 += __shfl_xor(a1, m, 64); a2 += __shfl_xor(a2, m, 64); a3 += __shfl_xor(a3, m, 64);
  }
  if ((tid & 63) == 0) { s1[tid >> 6] = a1; s2[tid >> 6] = a2; s3[tid >> 6] = a3; }
  __syncthreads();
  if (tid == 0) {
    db[o] = cb[o] + s1[0] + s1[1] + s1[2] + s1[3];
    bg[o] = cb[o] + s2[0] + s2[1] + s2[2] + s2[3];
    M1[o] = s3[0] + s3[1] + s3[2] + s3[3];
  }
}

// ---------------- k_cwT: transpose conv_w (256x256)
__global__ __launch_bounds__(256) void k_cwT(const float* __restrict__ cw,
                                             float* __restrict__ cwT) {
  __shared__ float tile[32][33];
  int bx = blockIdx.x & 7, by = blockIdx.x >> 3;
  int tid = threadIdx.x;
#pragma unroll
  for (int it = 0; it < 4; ++it) {
    int idx = it * 256 + tid, r = idx >> 5, c = idx & 31;
    tile[r][c] = cw[(size_t)(by * 32 + r) * Z_ + bx * 32 + c];
  }
  __syncthreads();
#pragma unroll
  for (int it = 0; it < 4; ++it) {
    int idx = it * 256 + tid, r = idx >> 5, c = idx & 31;
    cwT[(size_t)(bx * 32 + r) * Z_ + by * 32 + c] = tile[c][r];
  }
}

// ---------------- k_w1pack: A-fragments of w1^T, hi/lo split bf16 (contiguous k)
__global__ __launch_bounds__(64) void k_w1pack(const float* __restrict__ w1,
                                               short* __restrict__ wA) {
  int lane = threadIdx.x;
  int f = blockIdx.x;             // 48*24 = 1152
  int eg = f / 24, kkg = f % 24;
  int e = eg * 16 + (lane & 15);
  int d0 = kkg * 32 + 8 * (lane >> 4);
  ushort hh[8], ll[8];
#pragma unroll
  for (int j = 0; j < 8; ++j) {
    float v = w1[(size_t)(d0 + j) * D_ + e];
    hh[j] = f2bf(v);
    ll[j] = f2bf(v - bf2f(hh[j]));
  }
  int4v ph = {pk2(hh[0],hh[1]), pk2(hh[2],hh[3]), pk2(hh[4],hh[5]), pk2(hh[6],hh[7])};
  int4v pl = {pk2(ll[0],ll[1]), pk2(ll[2],ll[3]), pk2(ll[4],ll[5]), pk2(ll[6],ll[7])};
  int4v* W = (int4v*)wA;
  W[(size_t)f * 128 + lane] = ph;
  W[(size_t)f * 128 + 64 + lane] = pl;
}

// ---------------- k_mtpA: Mt[d][o] = sum_z wp[d][z]*cwT[z][o], packed A-frags (unrolled z)
__global__ __launch_bounds__(256) void k_mtpA(const float* __restrict__ wp,
                                              const float* __restrict__ cwT,
                                              short* __restrict__ mtA) {
  int o = threadIdx.x;
  int d0 = blockIdx.x * 8;
  int kkg = blockIdx.x >> 2, g = blockIdx.x & 3;
  float acc[8] = {0.f,0.f,0.f,0.f,0.f,0.f,0.f,0.f};
#pragma unroll 8
  for (int z = 0; z < Z_; ++z) {
    float c = cwT[(size_t)z * Z_ + o];
#pragma unroll
    for (int j = 0; j < 8; ++j) acc[j] += wp[(size_t)(d0 + j) * Z_ + z] * c;
  }
  int og = o >> 4, lane = (o & 15) + 16 * g;
  int4v p = {pk2(f2bf(acc[0]),f2bf(acc[1])), pk2(f2bf(acc[2]),f2bf(acc[3])),
             pk2(f2bf(acc[4]),f2bf(acc[5])), pk2(f2bf(acc[6]),f2bf(acc[7]))};
  ((int4v*)mtA)[(size_t)(og * 24 + kkg) * 64 + lane] = p;
}

// ---------------- k_score_mfma: score MFMA (split-bf16) + LN stats + raw bf16(x) write-through
// grid 256 (b x 16 tiles of 64 tokens), 512 thr = 8 waves (6 et x 4 tn each).
// Double-buffered 128-d chunks; prefetch next chunk's loads before MFMA (T14).
__global__ __launch_bounds__(512, 2) void k_score_mfma(const float* __restrict__ xin,
                                                       const short* __restrict__ wA,
                                                       const float* __restrict__ b1,
                                                       const float* __restrict__ w2,
                                                       const float* __restrict__ b2,
                                                       float* __restrict__ score,
                                                       float* __restrict__ scv,
                                                       float* __restrict__ shv,
                                                       short* __restrict__ xbf) {
  __shared__ short panH[2][64 * 128];        // 32 KB
  __shared__ short panL[2][64 * 128];        // 32 KB
  __shared__ float redS[8][16][4], redQ[8][16][4];
  __shared__ float redL[8][4][16];
  int tid = threadIdx.x;
  int wave = tid >> 6, lane = tid & 63;
  int g = lane >> 4, cc = lane & 15;
  int b = blockIdx.x >> 4;
  int n0 = (blockIdx.x & 15) * 64;
  const float* xb = xin + (size_t)b * D_ * N_ + n0;
  int qt = tid & 15, qd = tid >> 4;
  int t0 = qt * 4, dl0 = qd * 4;
  float ss[4] = {0.f,0.f,0.f,0.f}, sq[4] = {0.f,0.f,0.f,0.f};
  f32x4 acc[6][4];
#pragma unroll
  for (int et = 0; et < 6; ++et)
#pragma unroll
    for (int tn = 0; tn < 4; ++tn) acc[et][tn] = (f32x4){0.f,0.f,0.f,0.f};
  const int4v* Ab = (const int4v*)wA;
  int eg0 = wave * 6;
  float4 v0, v1, v2, v3;
#define LOADC(kc) { \
    v0 = *(const float4*)(xb + (size_t)((kc)*128 + dl0 + 0) * N_ + t0); \
    v1 = *(const float4*)(xb + (size_t)((kc)*128 + dl0 + 1) * N_ + t0); \
    v2 = *(const float4*)(xb + (size_t)((kc)*128 + dl0 + 2) * N_ + t0); \
    v3 = *(const float4*)(xb + (size_t)((kc)*128 + dl0 + 3) * N_ + t0); }
#define STG1(kc, bufsel, j, e0, e1, e2, e3) { \
    int t = t0 + (j); \
    int g1 = ((t & 7) ^ (t >> 3)); \
    int sb = t * 128 + (dl0 ^ (g1 << 3)); \
    ushort h0 = f2bf(e0), h1 = f2bf(e1), h2 = f2bf(e2), h3 = f2bf(e3); \
    short4v ph = {(short)h0,(short)h1,(short)h2,(short)h3}; \
    short4v pl = {(short)f2bf((e0)-bf2f(h0)), (short)f2bf((e1)-bf2f(h1)), \
                  (short)f2bf((e2)-bf2f(h2)), (short)f2bf((e3)-bf2f(h3))}; \
    *(short4v*)&panH[bufsel][sb] = ph; \
    *(short4v*)&panL[bufsel][sb] = pl; \
    *(short4v*)(xbf + ((size_t)(b * N_ + n0 + t)) * D_ + (kc)*128 + dl0) = ph; \
    ss[j] += (e0)+(e1)+(e2)+(e3); \
    sq[j] += (e0)*(e0)+(e1)*(e1)+(e2)*(e2)+(e3)*(e3); }
#define STGC(kc, bufsel) { \
    STG1(kc, bufsel, 0, v0.x, v1.x, v2.x, v3.x) \
    STG1(kc, bufsel, 1, v0.y, v1.y, v2.y, v3.y) \
    STG1(kc, bufsel, 2, v0.z, v1.z, v2.z, v3.z) \
    STG1(kc, bufsel, 3, v0.w, v1.w, v2.w, v3.w) }
  LOADC(0)
  STGC(0, 0)
  __syncthreads();
  for (int kc = 0; kc < 6; ++kc) {
    if (kc < 5) LOADC(kc + 1)                  // prefetch: latency hidden by MFMA below
    int bufsel = kc & 1;
#pragma unroll
    for (int kk = 0; kk < 4; ++kk) {
      bf16x8 Bh[4], Bl[4];
#pragma unroll
      for (int tn = 0; tn < 4; ++tn) {
        int t = tn * 16 + cc;
        int g1 = ((t & 7) ^ (t >> 3));
        int sb = t * 128 + ((kk * 32 + 8 * g) ^ (g1 << 3));
        Bh[tn] = *(const bf16x8*)&panH[bufsel][sb];
        Bl[tn] = *(const bf16x8*)&panL[bufsel][sb];
      }
#pragma unroll
      for (int et = 0; et < 6; ++et) {
        size_t fidx = ((size_t)((eg0 + et) * 24 + (kc * 4 + kk))) * 128 + lane;
        union { int4v i; bf16x8 v; } ah, al;
        ah.i = Ab[fidx];
        al.i = Ab[fidx + 64];
#pragma unroll
        for (int tn = 0; tn < 4; ++tn) {
          acc[et][tn] = __builtin_amdgcn_mfma_f32_16x16x32_bf16(ah.v, Bh[tn], acc[et][tn], 0, 0, 0);
          acc[et][tn] = __builtin_amdgcn_mfma_f32_16x16x32_bf16(ah.v, Bl[tn], acc[et][tn], 0, 0, 0);
          acc[et][tn] = __builtin_amdgcn_mfma_f32_16x16x32_bf16(al.v, Bh[tn], acc[et][tn], 0, 0, 0);
        }
      }
    }
    if (kc < 5) {
      STGC(kc + 1, bufsel ^ 1)
      __syncthreads();
    }
  }
#undef STGC
#undef STG1
#undef LOADC
  // ---- stats wave-reduce
#pragma unroll
  for (int j = 0; j < 4; ++j) {
    ss[j] += __shfl_xor(ss[j], 16, 64); sq[j] += __shfl_xor(sq[j], 16, 64);
    ss[j] += __shfl_xor(ss[j], 32, 64); sq[j] += __shfl_xor(sq[j], 32, 64);
  }
  if (lane < 16) {
#pragma unroll
    for (int j = 0; j < 4; ++j) { redS[wave][lane][j] = ss[j]; redQ[wave][lane][j] = sq[j]; }
  }
  // ---- logits: relu + dot(w2)
  float lg[4] = {0.f,0.f,0.f,0.f};
#pragma unroll
  for (int et = 0; et < 6; ++et) {
    int e = (eg0 + et) * 16 + 4 * g;
    float4 bb = *(const float4*)(b1 + e);
    float4 ww = *(const float4*)(w2 + e);
#pragma unroll
    for (int tn = 0; tn < 4; ++tn) {
      lg[tn] += fmaxf(acc[et][tn][0] + bb.x, 0.f) * ww.x;
      lg[tn] += fmaxf(acc[et][tn][1] + bb.y, 0.f) * ww.y;
      lg[tn] += fmaxf(acc[et][tn][2] + bb.z, 0.f) * ww.z;
      lg[tn] += fmaxf(acc[et][tn][3] + bb.w, 0.f) * ww.w;
    }
  }
#pragma unroll
  for (int tn = 0; tn < 4; ++tn) {
    lg[tn] += __shfl_xor(lg[tn], 16, 64);
    lg[tn] += __shfl_xor(lg[tn], 32, 64);
  }
  if (lane < 16) {
#pragma unroll
    for (int tn = 0; tn < 4; ++tn) redL[wave][tn][lane] = lg[tn];
  }
  __syncthreads();
  if (tid < 64) {
    int t = tid;
    float S = 0.f, Q = 0.f, L = 0.f;
#pragma unroll
    for (int w = 0; w < 8; ++w) {
      S += redS[w][t >> 2][t & 3];
      Q += redQ[w][t >> 2][t & 3];
      L += redL[w][t >> 4][t & 15];
    }
    float mu = S * (1.f / D_);
    float var = Q * (1.f / D_) - mu * mu;
    float rs = rsqrtf(var + EPS_);
    float sv = 1.f / (1.f + expf(-(L + b2[0])));
    int n = b * N_ + n0 + t;
    float sc = rs * sv;
    score[n] = sv;
    scv[n] = sc;
    shv[n] = -mu * sc;
  }
}

// ---------------- k_select: exact rank (stable argsort(-s) semantics) + batch min/max
__global__ __launch_bounds__(1024) void k_select(const float* __restrict__ score,
                                                 int* __restrict__ rank,
                                                 float* __restrict__ mm) {
  __shared__ float s[N_];
  __shared__ float red[32];
  int tid = threadIdx.x;
  int b = blockIdx.x >> 2;
  int tg = blockIdx.x & 3;
  s[tid] = score[b * N_ + tid];
  __syncthreads();
  int token = tg * 256 + (tid >> 2);
  int jq = tid & 3;
  float si = s[token];
  int cnt = 0;
  int j0 = jq * 256;
  for (int j = j0; j < j0 + 256; j += 4) {
    float4 sj = *reinterpret_cast<const float4*>(&s[j]);
    cnt += (sj.x > si) || (sj.x == si && (j + 0) < token);
    cnt += (sj.y > si) || (sj.y == si && (j + 1) < token);
    cnt += (sj.z > si) || (sj.z == si && (j + 2) < token);
    cnt += (sj.w > si) || (sj.w == si && (j + 3) < token);
  }
  cnt += __shfl_xor(cnt, 1, 64);
  cnt += __shfl_xor(cnt, 2, 64);
  if (jq == 0) rank[b * N_ + token] = cnt;
  if (tg == 0) {
    float v = s[tid];
    float mn = v, mx = v;
#pragma unroll
    for (int off = 32; off > 0; off >>= 1) {
      mn = fminf(mn, __shfl_xor(mn, off, 64));
      mx = fmaxf(mx, __shfl_xor(mx, off, 64));
    }
    if ((tid & 63) == 0) { red[tid >> 6] = mn; red[16 + (tid >> 6)] = mx; }
    __syncthreads();
    if (tid == 0) {
      float a = red[0], c = red[16];
      for (int w = 1; w < 16; ++w) { a = fminf(a, red[w]); c = fmaxf(c, red[16 + w]); }
      mm[2 * b] = a; mm[2 * b + 1] = c;
    }
  }
}

// ---------------- k_gemm2dec: out[b][o][n] = sel ? scv[n]*(sum_d x̂·Mt) + shv[n]*M1[o] + db[o] : bg[o]
// grid 256: b(16) x kt(16 tiles of 64 tokens). 512 thr = 8 waves (2 og x 4 tn). Double-buffered.
__global__ __launch_bounds__(512, 2) void k_gemm2dec(const short* __restrict__ xbf,
                                                     const short* __restrict__ mtA,
                                                     const float* __restrict__ db,
                                                     const float* __restrict__ bg,
                                                     const float* __restrict__ M1,
                                                     const float* __restrict__ scv,
                                                     const float* __restrict__ shv,
                                                     const int* __restrict__ rank,
                                                     float* __restrict__ out) {
  __shared__ short pan[2][64 * 128];   // 32 KB
  __shared__ float lsc[64], lsh[64];
  __shared__ int lrk[64];
  int tid = threadIdx.x;
  int wave = tid >> 6, lane = tid & 63;
  int g = lane >> 4, cc = lane & 15;
  int b = blockIdx.x >> 4;
  int n0 = (blockIdx.x & 15) * 64;
  if (tid < 64) {
    int n = b * N_ + n0 + tid;
    lsc[tid] = scv[n]; lsh[tid] = shv[n]; lrk[tid] = rank[n];
  }
  int srow = tid >> 3, scol = (tid & 7) * 16;
  int sg1 = ((srow & 7) ^ (srow >> 3)) << 3;
  const short* gb = xbf + (size_t)(b * N_ + n0) * D_;
  f32x4 acc[2][4];
#pragma unroll
  for (int et = 0; et < 2; ++et)
#pragma unroll
    for (int tn = 0; tn < 4; ++tn) acc[et][tn] = (f32x4){0.f,0.f,0.f,0.f};
  const int4v* Am = (const int4v*)mtA;
  int4v u0, u1;
#define GLOAD(kc) { \
    u0 = *(const int4v*)(gb + (size_t)srow * D_ + (kc)*128 + scol); \
    u1 = *(const int4v*)(gb + (size_t)srow * D_ + (kc)*128 + scol + 8); }
#define PSTORE(bufsel) { \
    *(int4v*)&pan[bufsel][srow * 128 + (scol ^ sg1)] = u0; \
    *(int4v*)&pan[bufsel][srow * 128 + ((scol + 8) ^ sg1)] = u1; }
  GLOAD(0)
  PSTORE(0)
  __syncthreads();
  for (int kc = 0; kc < 6; ++kc) {
    if (kc < 5) GLOAD(kc + 1)
    int bufsel = kc & 1;
#pragma unroll
    for (int kk = 0; kk < 4; ++kk) {
      bf16x8 Bv[4];
#pragma unroll
      for (int tn = 0; tn < 4; ++tn) {
        int t = tn * 16 + cc;
        int g1 = ((t & 7) ^ (t >> 3));
        Bv[tn] = *(const bf16x8*)&pan[bufsel][t * 128 + ((kk * 32 + 8 * g) ^ (g1 << 3))];
      }
#pragma unroll
      for (int et = 0; et < 2; ++et) {
        int og = wave * 2 + et;
        size_t fidx = ((size_t)(og * 24 + (kc * 4 + kk))) * 64 + lane;
        union { int4v i; bf16x8 v; } av; av.i = Am[fidx];
#pragma unroll
        for (int tn = 0; tn < 4; ++tn)
          acc[et][tn] = __builtin_amdgcn_mfma_f32_16x16x32_bf16(av.v, Bv[tn], acc[et][tn], 0, 0, 0);
      }
    }
    if (kc < 5) {
      PSTORE(bufsel ^ 1)
      __syncthreads();
    }
  }
#undef GLOAD
#undef PSTORE
#pragma unroll
  for (int et = 0; et < 2; ++et) {
    int og = wave * 2 + et;
    int o0 = og * 16 + 4 * g;
    float4 dbv = *(const float4*)(db + o0);
    float4 bgv = *(const float4*)(bg + o0);
    float4 m1v = *(const float4*)(M1 + o0);
#pragma unroll
    for (int r = 0; r < 4; ++r) {
      int o = o0 + r;
      float dbr = ((const float*)&dbv)[r], bgr = ((const float*)&bgv)[r], m1r = ((const float*)&m1v)[r];
      float* orow = out + ((size_t)(b * Z_ + o)) * N_ + n0 + cc;
#pragma unroll
      for (int tn = 0; tn < 4; ++tn) {
        int tl = tn * 16 + cc;
        float v = (lrk[tl] < TOPK_) ? lsc[tl] * acc[et][tn][r] + lsh[tl] * m1r + dbr : bgr;
        orow[tn * 16] = v;
      }
    }
  }
}

// ---------------- k_maps: binary_map + score_map (nearest upsample x16)
__global__ __launch_bounds__(128) void k_maps(const float* __restrict__ score,
                                              const int* __restrict__ rank,
                                              const float* __restrict__ mm,
                                              float* __restrict__ out) {
  int tid = threadIdx.x;
  int b = blockIdx.x >> 9;
  int ph = blockIdx.x & 511;
  float mn = mm[0], mx = mm[1];
#pragma unroll
  for (int w = 1; w < 16; ++w) { mn = fminf(mn, mm[2 * w]); mx = fmaxf(mx, mm[2 * w + 1]); }
  float inv = 1.f / fmaxf(mx - mn, EPS_);
  int pw0 = tid * 4;
  int cell = (ph >> 4) * HW_ + (pw0 >> 4);
  int rk = rank[b * N_ + cell];
  float bin = (rk < TOPK_) ? 1.f : 0.f;
  float sv = (score[b * N_ + cell] - mn) * inv;
  size_t base = (size_t)b * (512 * 512) + (size_t)ph * 512 + pw0;
  float4 bv = {bin, bin, bin, bin};
  float4 svv = {sv, sv, sv, sv};
  *reinterpret_cast<float4*>(out + 4194304 + base) = bv;
  *reinterpret_cast<float4*>(out + 8388608 + base) = svv;
}

extern "C" void kernel_launch(void* const* d_in, const int* in_sizes, int n_in,
                              void* d_out, int out_size, void* d_ws, size_t ws_size,
                              hipStream_t stream) {
  const float* xin = (const float*)d_in[0];
  const float* w1  = (const float*)d_in[1];
  const float* b1  = (const float*)d_in[2];
  const float* w2  = (const float*)d_in[3];
  const float* b2  = (const float*)d_in[4];
  const float* wp  = (const float*)d_in[5];
  const float* bp  = (const float*)d_in[6];
  const float* mtk = (const float*)d_in[7];
  const float* cw  = (const float*)d_in[8];
  const float* cb  = (const float*)d_in[9];
  float* out = (float*)d_out;

  short* wA    = (short*)d_ws;                // 1,179,648 shorts
  short* mtA   = wA + 1179648;                // 196,608 shorts
  short* xbf   = mtA + 196608;                // 12,582,912 shorts (bf16 x, token-major)
  float* cwT   = (float*)(xbf + 12582912);    // 65,536
  float* wsum4 = cwT + 65536;                 // 1,024
  float* db    = wsum4 + 1024;                // 256
  float* bg    = db + 256;                    // 256
  float* M1    = bg + 256;                    // 256
  float* score = M1 + 256;                    // 16,384
  float* scv   = score + 16384;               // 16,384
  float* shv   = scv + 16384;                 // 16,384
  float* mm    = shv + 16384;                 // 32
  int*   rank  = (int*)(mm + 32);             // 16,384
  // total ~28.7 MB

  k_wsum      <<<dim3(4),    dim3(256),  0, stream>>>(wp, wsum4);
  k_db        <<<dim3(256),  dim3(256),  0, stream>>>(cw, cb, bp, mtk, wsum4, db, bg, M1);
  k_cwT       <<<dim3(64),   dim3(256),  0, stream>>>(cw, cwT);
  k_mtpA      <<<dim3(96),   dim3(256),  0, stream>>>(wp, cwT, mtA);
  k_w1pack    <<<dim3(1152), dim3(64),   0, stream>>>(w1, wA);
  k_score_mfma<<<dim3(256),  dim3(512),  0, stream>>>(xin, wA, b1, w2, b2, score, scv, shv, xbf);
  k_select    <<<dim3(64),   dim3(1024), 0, stream>>>(score, rank, mm);
  k_gemm2dec  <<<dim3(256),  dim3(512),  0, stream>>>(xbf, mtA, db, bg, M1, scv, shv, rank, out);
  k_maps      <<<dim3(8192), dim3(128),  0, stream>>>(score, rank, mm, out);
}